// Round 10
// baseline (1018.316 us; speedup 1.0000x reference)
//
#include <hip/hip_runtime.h>
#include <hip/hip_bf16.h>
#include <math.h>

typedef __attribute__((ext_vector_type(8))) __bf16 bf16x8;
typedef __attribute__((ext_vector_type(4))) __bf16 bf16x4;
typedef __attribute__((ext_vector_type(4))) float f32x4;

#define MPAD 20224
#define SHS ((size_t)MPAD * 64)   // shard stride, 64-col shard-major: [shard][row][64]
                                  // slab = MPAD*64*2B = 2.6 MB -> fully fits 4MB XCD L2

#if __has_builtin(__builtin_amdgcn_global_load_lds)
#define GLD16(g, l)                                                                      \
    __builtin_amdgcn_global_load_lds(                                                    \
        (const __attribute__((address_space(1))) unsigned int*)(g),                      \
        (__attribute__((address_space(3))) unsigned int*)(l), 16, 0, 0)
#else
// host-pass / fallback: synchronous 16B copy (semantically equivalent)
#define GLD16(g, l) (*(bf16x8*)(l) = *(const bf16x8*)(g))
#endif

#define BAR() asm volatile("s_barrier" ::: "memory")
#define WAITVM(N) asm volatile("s_waitcnt vmcnt(" #N ")" ::: "memory")

// =====================================================================================
// 256x256 8-wave GEMM, BK=32, QUAD-buffered LDS — round-4 schedule (measured 104-107us,
// 0 bank conflicts, VGPR=100, acc in AGPRs). Unchanged except epilogue layout (64-col
// shard-major C).
// vmcnt ledger (4 loads per stage): prologue stages tiles 0,1,2 then vmcnt(8) lands
// tile 0. Body t: issue stage(t+3); LOAD_FRAGS(t); MFMA; vmcnt(8) lands stage(t+1).
// Tail: vmcnt(4)/vmcnt(0). Never drains mid-loop.
// =====================================================================================

#define STAGE_T(t_)                                                                      \
    do {                                                                                 \
        __bf16* Ld = lds + (((t_) & 3) * 16384);                                         \
        const __bf16* Ga = Abase + (t_) * 32;                                            \
        const __bf16* Gb = Bbase + (t_) * 32;                                            \
        GLD16(Ga, Ld + tt * 8);                                                          \
        GLD16(Ga + (size_t)128 * K_, Ld + (tt + 512) * 8);                               \
        GLD16(Gb, Ld + 8192 + tt * 8);                                                   \
        GLD16(Gb + (size_t)128 * K_, Ld + 8192 + (tt + 512) * 8);                        \
    } while (0)

#define LOAD_FRAGS(t_)                                                                   \
    {                                                                                    \
        const __bf16* Ar = lds + (((t_) & 3) * 16384) + aoff;                            \
        const __bf16* Br = lds + (((t_) & 3) * 16384) + 8192 + boff;                     \
        _Pragma("unroll") for (int i = 0; i < 8; i++)                                    \
            af[i] = *(const bf16x8*)(Ar + i * 512);                                      \
        _Pragma("unroll") for (int j = 0; j < 4; j++)                                    \
            bf[j] = *(const bf16x8*)(Br + j * 512);                                      \
    }

#define MFMA_ALL()                                                                       \
    __builtin_amdgcn_s_setprio(1);                                                       \
    _Pragma("unroll") for (int i = 0; i < 8; i++)                                        \
        _Pragma("unroll") for (int j = 0; j < 4; j++)                                    \
            acc[i][j] = __builtin_amdgcn_mfma_f32_16x16x32_bf16(af[i], bf[j],            \
                                                                acc[i][j], 0, 0, 0);     \
    __builtin_amdgcn_s_setprio(0);

#define GEMM256_BODY(A, Bt, K_, ...)                                                     \
    __shared__ __align__(16) __bf16 lds[65536];                                          \
    const int tt = threadIdx.x;                                                          \
    const int lane = tt & 63;                                                            \
    const int wid = tt >> 6;                                                             \
    const int wr = wid >> 2; /* 0..1: M half */                                          \
    const int wc = wid & 3;  /* 0..3: N quarter */                                       \
    /* T1: bijective XCD swizzle (m204) so col-tiles sharing an A panel stay on 1 XCD */ \
    const int nwg = gridDim.x * gridDim.y;                                               \
    const int wg0 = blockIdx.y * gridDim.x + blockIdx.x;                                 \
    const int qq = nwg >> 3, rr = nwg & 7, xcd = wg0 & 7, oo = wg0 >> 3;                 \
    const int swz = (xcd < rr ? xcd * (qq + 1) : rr * (qq + 1) + (xcd - rr) * qq) + oo;  \
    const int bm = (swz / gridDim.x) * 256;                                              \
    const int bn = (swz % gridDim.x) * 256;                                              \
    const int m16 = lane & 15;                                                           \
    const int c4 = lane >> 4;                                                            \
    const int NT = K_ >> 5;                                                              \
    const int ttp = tt ^ (((tt >> 5) & 1) << 1); /* pre-swizzled source chunk */         \
    const int srow = ttp >> 2;                                                           \
    const int sch = (ttp & 3) << 3;                                                      \
    const __bf16* Abase = A + (size_t)(bm + srow) * K_ + sch;                            \
    const __bf16* Bbase = Bt + (size_t)(bn + srow) * K_ + sch;                           \
    const int fsw = ((m16 >> 3) & 1) << 4;                                               \
    const int aoff = (((wr * 128 + m16) * 32) + c4 * 8) ^ fsw;                           \
    const int boff = (((wc * 64 + m16) * 32) + c4 * 8) ^ fsw;                            \
    f32x4 acc[8][4];                                                                     \
    _Pragma("unroll") for (int i = 0; i < 8; i++)                                        \
        _Pragma("unroll") for (int j = 0; j < 4; j++)                                    \
            acc[i][j] = (f32x4){0.f, 0.f, 0.f, 0.f};                                     \
    bf16x8 af[8], bf[4];                                                                 \
    /* prologue: stage tiles 0..2; land tile 0; keep {1,2} in flight */                  \
    STAGE_T(0);                                                                          \
    if (NT > 1) STAGE_T(1);                                                              \
    if (NT > 2) STAGE_T(2);                                                              \
    if (NT > 2) { WAITVM(8); } else if (NT > 1) { WAITVM(4); } else { WAITVM(0); }       \
    BAR();                                                                               \
    for (int t = 0; t < NT; t++) {                                                       \
        if (t + 3 < NT) STAGE_T(t + 3);                                                  \
        LOAD_FRAGS(t);                                                                   \
        MFMA_ALL();                                                                      \
        if (t + 1 < NT) {                                                                \
            if (t + 3 < NT) { WAITVM(8); }                                               \
            else if (t + 3 == NT) { WAITVM(4); }                                         \
            else { WAITVM(0); }                                                          \
            BAR();                                                                       \
        }                                                                                \
    }                                                                                    \
    __VA_ARGS__

// Single-output (layer 3): C shard-major [col>>6][row][64], cols < 768 (12 shards)
__global__ __launch_bounds__(512, 2) void gemm256_bt(const __bf16* __restrict__ A,
                                                     const __bf16* __restrict__ Bt,
                                                     __bf16* __restrict__ C,
                                                     int M, int N_, int K_) {
    GEMM256_BODY(A, Bt, K_,
        { const int r4 = c4 << 2;
          const int rb = bm + wr * 128;
          _Pragma("unroll") for (int i = 0; i < 8; i++)
              _Pragma("unroll") for (int j = 0; j < 4; j++) {
                  int col = bn + wc * 64 + j * 16 + m16;
                  size_t sb_ = (size_t)(col >> 6) * SHS + (col & 63);
                  _Pragma("unroll") for (int r = 0; r < 4; r++) {
                      int row = rb + i * 16 + r4 + r;
                      C[sb_ + (size_t)row * 64] = (__bf16)acc[i][j][r];
                  }
              } })
}

// Dual-output: Bt 2048 rows; cols 0-1023 -> C0, 1024-2047 -> C1, 16 shards of 64 each
__global__ __launch_bounds__(512, 2) void gemm256_bt2(const __bf16* __restrict__ A,
                                                      const __bf16* __restrict__ Bt,
                                                      __bf16* __restrict__ C0,
                                                      __bf16* __restrict__ C1,
                                                      int M, int K_) {
    GEMM256_BODY(A, Bt, K_,
        { const int r4 = c4 << 2;
          const int rb = bm + wr * 128;
          _Pragma("unroll") for (int i = 0; i < 8; i++)
              _Pragma("unroll") for (int j = 0; j < 4; j++) {
                  int col = bn + wc * 64 + j * 16 + m16;
                  __bf16* Cp = (col < 1024) ? C0 : C1;
                  int c10 = col & 1023;
                  size_t sb_ = (size_t)(c10 >> 6) * SHS + (c10 & 63);
                  _Pragma("unroll") for (int r = 0; r < 4; r++) {
                      int row = rb + i * 16 + r4 + r;
                      Cp[sb_ + (size_t)row * 64] = (__bf16)acc[i][j][r];
                  }
              } })
}

// ---------------- combined prep: pack x + all weight transposes, one launch ----------
__device__ __forceinline__ void transpose_tile(const float* __restrict__ W,
                                               __bf16* __restrict__ WT,
                                               int K, int N, int Kp, int Np,
                                               int bx, int by, float* sm) {
    int tx = threadIdx.x & 31, ty = threadIdx.x >> 5;
#pragma unroll
    for (int r = ty; r < 32; r += 8) {
        int k = by * 32 + r, n = bx * 32 + tx;
        float v = 0.f;
        if (k < K && n < N) v = W[(size_t)k * N + n];
        sm[r * 33 + tx] = v;
    }
    __syncthreads();
#pragma unroll
    for (int r = ty; r < 32; r += 8) {
        int n = bx * 32 + r, k = by * 32 + tx;
        if (n < Np && k < Kp) WT[(size_t)n * Kp + k] = (__bf16)sm[tx * 33 + r];
    }
}

__device__ __forceinline__ void transpose_w3_tile(const float* __restrict__ W,
                                                  __bf16* __restrict__ WT,
                                                  int bx, int by, float* sm) {
    int tx = threadIdx.x & 31, ty = threadIdx.x >> 5;
    int r0 = bx * 32;
    int h = r0 >> 7;
    int c0 = r0 & 127;
#pragma unroll
    for (int r = ty; r < 32; r += 8) {
        int k = by * 32 + r;
        int c = c0 + tx;
        float v = 0.f;
        if (c < 121) v = W[(size_t)k * 726 + h * 121 + c];
        sm[r * 33 + tx] = v;
    }
    __syncthreads();
#pragma unroll
    for (int r = ty; r < 32; r += 8) {
        int rr = r0 + r;
        int k = by * 32 + tx;
        WT[(size_t)rr * 1024 + k] = (__bf16)sm[tx * 33 + r];
    }
}

__global__ __launch_bounds__(256) void prep_k(const float* __restrict__ x,
                                              const float* __restrict__ W1,
                                              const float* __restrict__ sW1,
                                              const float* __restrict__ W2,
                                              const float* __restrict__ sW2,
                                              const float* __restrict__ W3,
                                              __bf16* __restrict__ xp,
                                              __bf16* __restrict__ WTcat1,
                                              __bf16* __restrict__ WTcat2,
                                              __bf16* __restrict__ W3pT, int Nn) {
    __shared__ float sm[32 * 33];
    int b = blockIdx.x;
    if (b < 5056) {                       // xp: 20224 rows x 64 cols
        int i = b * 256 + threadIdx.x;
        int n = i >> 6, c = i & 63;
        float v = 0.f;
        if (n < Nn && c < 50) v = x[n * 50 + c];
        xp[(size_t)n * 64 + c] = (__bf16)v;
    } else if (b < 5120) {
        int i = b - 5056; transpose_tile(W1, WTcat1, 50, 1024, 64, 1024, i % 32, i / 32, sm);
    } else if (b < 5184) {
        int i = b - 5120; transpose_tile(sW1, WTcat1 + 1024 * 64, 50, 1024, 64, 1024, i % 32, i / 32, sm);
    } else if (b < 6208) {
        int i = b - 5184; transpose_tile(W2, WTcat2, 1024, 1024, 1024, 1024, i % 32, i / 32, sm);
    } else if (b < 7232) {
        int i = b - 6208; transpose_tile(sW2, WTcat2 + (size_t)1024 * 1024, 1024, 1024, 1024, 1024, i % 32, i / 32, sm);
    } else {
        int i = b - 7232; transpose_w3_tile(W3, W3pT, i % 24, i / 24, sm);
    }
}

// ---------------- CSR build (by dst, self-loops appended, degree padded to x8) ----------
__global__ void zero_probe_k(const int* __restrict__ ei, int* __restrict__ cnt,
                             int* __restrict__ flag, int Nn) {
    int i = blockIdx.x * 256 + threadIdx.x;
    if (i < Nn) cnt[i] = 0;
    if (blockIdx.x == 0 && threadIdx.x == 0) {
        int all0 = 1;
        for (int k = 0; k < 64; k++)
            if (ei[2 * k + 1] != 0) { all0 = 0; break; }
        *flag = all0;
    }
}

__device__ __forceinline__ int load_ei(const int* ei, int idx, int is64) {
    return is64 ? ei[2 * idx] : ei[idx];
}

__global__ void hist_k(const int* __restrict__ ei, const int* __restrict__ flag,
                       int* __restrict__ cnt, int E, int Nn) {
    int e = blockIdx.x * 256 + threadIdx.x;
    if (e >= E + Nn) return;
    int is64 = *flag;
    int d = (e < E) ? load_ei(ei, E + e, is64) : (e - E);
    d = min(max(d, 0), Nn - 1);
    atomicAdd(&cnt[d], 1);
}

// exclusive scan over x8-PADDED counts; zeros cnt afterwards (cursor for fill)
__global__ __launch_bounds__(1024) void scan_k(int* __restrict__ cnt, int* __restrict__ row_ptr,
                                               int Nn) {
    __shared__ int part[1024];
    int t = threadIdx.x;
    int chunk = (Nn + 1023) >> 10;
    int lo = t * chunk;
    int hi = lo + chunk; if (hi > Nn) hi = Nn; if (lo > Nn) lo = Nn;
    int s = 0;
    for (int i = lo; i < hi; i++) s += (cnt[i] + 7) & ~7;
    part[t] = s;
    __syncthreads();
    for (int off = 1; off < 1024; off <<= 1) {
        int v = (t >= off) ? part[t - off] : 0;
        __syncthreads();
        part[t] += v;
        __syncthreads();
    }
    int run = part[t] - s;
    for (int i = lo; i < hi; i++) { row_ptr[i] = run; run += (cnt[i] + 7) & ~7; }
    if (t == 1023) row_ptr[Nn] = part[1023];
    __syncthreads();
    for (int i = lo; i < hi; i++) cnt[i] = 0;
}

__global__ void fill_csr_k(const int* __restrict__ ei, const int* __restrict__ flag,
                           const int* __restrict__ row_ptr, int* __restrict__ cursor,
                           int* __restrict__ src_csr, int E, int Nn) {
    int e = blockIdx.x * 256 + threadIdx.x;
    if (e >= E + Nn) return;
    int is64 = *flag;
    int d = (e < E) ? load_ei(ei, E + e, is64) : (e - E);
    int s = (e < E) ? load_ei(ei, e, is64) : (e - E);
    d = min(max(d, 0), Nn - 1);
    s = min(max(s, 0), Nn - 1);
    int slot = row_ptr[d] + atomicAdd(&cursor[d], 1);
    src_csr[slot] = s;
}

// ------- per-(node,head) attention dots (64-col shard-major XL; sph = shards/head) ----
__global__ void alpha_k(const __bf16* __restrict__ XL, int sph, const float* __restrict__ a_src,
                        const float* __restrict__ a_dst, float* __restrict__ asrc,
                        float* __restrict__ adst, int Nn, int H, int C) {
    int gw = (blockIdx.x * 256 + threadIdx.x) >> 6;
    int lane = threadIdx.x & 63;
    if (gw >= Nn * H) return;
    int n = gw / H, h = gw - n * H;
    const float* as = a_src + h * C;
    const float* ad = a_dst + h * C;
    float s = 0.f, d = 0.f;
    for (int c = lane; c < C; c += 64) {
        float v = (float)XL[(size_t)(h * sph + (c >> 6)) * SHS + (size_t)n * 64 + (c & 63)];
        s += v * as[c];
        d += v * ad[c];
    }
#pragma unroll
    for (int off = 32; off; off >>= 1) {
        s += __shfl_down(s, off);
        d += __shfl_down(d, off);
    }
    if (lane == 0) { asrc[n * H + h] = s; adst[n * H + h] = d; }
}

// ------- per-node segment softmax -> transposed edge weights wt[h][Ecap] ----------
__global__ void attn_k(const int* __restrict__ row_ptr, const int* __restrict__ deg,
                       const int* __restrict__ src_csr,
                       const float* __restrict__ asrc, const float* __restrict__ adst,
                       float* __restrict__ wt, int Nn, int H, int Ecap) {
    int gw = (blockIdx.x * 256 + threadIdx.x) >> 6;
    int lane = threadIdx.x & 63;
    if (gw >= Nn) return;
    int n = gw;
    int base = row_ptr[n], dg = deg[n];
    if (dg <= 64) {
        // fast path: one edge per lane, single pass
        bool v = lane < dg;
        int src = v ? src_csr[base + lane] : 0;
        for (int h = 0; h < H; h++) {
            float ad = adst[n * H + h];
            float e = -1e30f;
            if (v) {
                e = asrc[src * H + h] + ad;
                e = e > 0.f ? e : 0.2f * e;
            }
            float m = e;
#pragma unroll
            for (int off = 1; off < 64; off <<= 1) m = fmaxf(m, __shfl_xor(m, off));
            float ex = v ? __expf(e - m) : 0.f;
            float sum = ex;
#pragma unroll
            for (int off = 1; off < 64; off <<= 1) sum += __shfl_xor(sum, off);
            if (v) wt[(size_t)h * Ecap + base + lane] = ex / (sum + 1e-16f);
        }
        return;
    }
    for (int h = 0; h < H; h++) {
        float ad = adst[n * H + h];
        float m = -1e30f;
        for (int s = lane; s < dg; s += 64) {
            float e = asrc[src_csr[base + s] * H + h] + ad;
            e = e > 0.f ? e : 0.2f * e;
            m = fmaxf(m, e);
        }
#pragma unroll
        for (int off = 1; off < 64; off <<= 1) m = fmaxf(m, __shfl_xor(m, off));
        float sum = 0.f;
        for (int s = lane; s < dg; s += 64) {
            float e = asrc[src_csr[base + s] * H + h] + ad;
            e = e > 0.f ? e : 0.2f * e;
            sum += __expf(e - m);
        }
#pragma unroll
        for (int off = 1; off < 64; off <<= 1) sum += __shfl_xor(sum, off);
        float inv = 1.f / (sum + 1e-16f);
        float* wrow = wt + (size_t)h * Ecap;
        for (int s = lane; s < dg; s += 64) {
            float e = asrc[src_csr[base + s] * H + h] + ad;
            e = e > 0.f ? e : 0.2f * e;
            wrow[base + s] = __expf(e - m) * inv;
        }
    }
}

// ------- shard-major aggregation, layers 1/2 (16 shards of 64 cols), x8-padded CSR ----
// 2D grid (nodeBlocks, 16), cc = blockIdx.y: x-fastest dispatch temporally clusters
// same-shard blocks, so ALL XCDs work one 2.6MB slab at a time (fully L2-resident;
// robust to undefined block->XCD assignment — the r9 1D bid&7 pinning regressed).
__global__ __launch_bounds__(256) void agg_skip8(const __bf16* __restrict__ XL,
                                                 const float* __restrict__ wt,
                                                 const int* __restrict__ row_ptr,
                                                 const int* __restrict__ src_csr,
                                                 const float* __restrict__ bias,
                                                 const float* __restrict__ sb,
                                                 __bf16* __restrict__ SK, int Nn, int Ecap) {
    const int cc = blockIdx.y;                 // 0..15
    const int n = blockIdx.x * 4 + (threadIdx.x >> 6);
    const int lane = threadIdx.x & 63;
    if (n >= Nn) return;
    const int g = lane >> 4;                   // edge group 0..3, 2 contiguous edges each
    const int p = lane & 15;
    const int col = cc * 64 + p * 4;
    const float* wrow = wt + (size_t)(cc >> 2) * Ecap;
    const __bf16* XLc = XL + (size_t)cc * SHS + p * 4;
    const int base = row_ptr[n], end = row_ptr[n + 1];

    float acc[4];
#pragma unroll
    for (int j = 0; j < 4; j++) acc[j] = 0.f;

    for (int e = base; e < end; e += 8) {
        int2 si = *(const int2*)(src_csr + e + 2 * g);
        float2 wv = *(const float2*)(wrow + e + 2 * g);
        bf16x4 xa = *(const bf16x4*)(XLc + (size_t)si.x * 64);
        bf16x4 xb = *(const bf16x4*)(XLc + (size_t)si.y * 64);
#pragma unroll
        for (int j = 0; j < 4; j++) acc[j] += wv.x * (float)xa[j] + wv.y * (float)xb[j];
    }
#pragma unroll
    for (int j = 0; j < 4; j++) {
        acc[j] += __shfl_xor(acc[j], 16);
        acc[j] += __shfl_xor(acc[j], 32);
    }
    if (lane < 16) {
        size_t o = (size_t)cc * SHS + (size_t)n * 64 + p * 4;
        bf16x4 sk = *(const bf16x4*)(SK + o);
        bf16x4 res;
#pragma unroll
        for (int j = 0; j < 4; j++)
            res[j] = (__bf16)(acc[j] + bias[col + j] + sb[col + j] + (float)sk[j]);
        *(bf16x4*)(SK + o) = res;
    }
}

// ------- layer-3 aggregation, shard-major xl [12][MPAD][64] -> bf16 partials [n][768] --
__global__ __launch_bounds__(256) void agg_mean8(const __bf16* __restrict__ XL,
                                                 const float* __restrict__ wt,
                                                 const int* __restrict__ row_ptr,
                                                 const int* __restrict__ src_csr,
                                                 __bf16* __restrict__ part, int Nn, int Ecap) {
    const int cc = blockIdx.y;                 // 0..11 (head = cc>>1)
    const int n = blockIdx.x * 4 + (threadIdx.x >> 6);
    const int lane = threadIdx.x & 63;
    if (n >= Nn) return;
    const int g = lane >> 4;
    const int p = lane & 15;
    const int col = cc * 64 + p * 4;
    const float* wrow = wt + (size_t)(cc >> 1) * Ecap;
    const __bf16* XLc = XL + (size_t)cc * SHS + p * 4;
    const int base = row_ptr[n], end = row_ptr[n + 1];

    float acc[4];
#pragma unroll
    for (int j = 0; j < 4; j++) acc[j] = 0.f;

    for (int e = base; e < end; e += 8) {
        int2 si = *(const int2*)(src_csr + e + 2 * g);
        float2 wv = *(const float2*)(wrow + e + 2 * g);
        bf16x4 xa = *(const bf16x4*)(XLc + (size_t)si.x * 64);
        bf16x4 xb = *(const bf16x4*)(XLc + (size_t)si.y * 64);
#pragma unroll
        for (int j = 0; j < 4; j++) acc[j] += wv.x * (float)xa[j] + wv.y * (float)xb[j];
    }
#pragma unroll
    for (int j = 0; j < 4; j++) {
        acc[j] += __shfl_xor(acc[j], 16);
        acc[j] += __shfl_xor(acc[j], 32);
    }
    if (lane < 16) {
        size_t o = (size_t)n * 768 + col;
        bf16x4 res;
#pragma unroll
        for (int j = 0; j < 4; j++) res[j] = (__bf16)acc[j];
        *(bf16x4*)(part + o) = res;
    }
}

// -------- head-mean over bf16 partials (head stride 128) + bias -> fp32 out --------
__global__ __launch_bounds__(128) void reduce_mean_k(const __bf16* __restrict__ part,
                                                     const float* __restrict__ b3,
                                                     float* __restrict__ out, int Nn) {
    int n = blockIdx.x;
    int t = threadIdx.x;
    if (t >= 121) return;
    const __bf16* row = part + (size_t)n * 768;
    float s = 0.f;
#pragma unroll
    for (int h = 0; h < 6; h++) s += (float)row[h * 128 + t];
    out[(size_t)n * 121 + t] = s * (1.f / 6.f) + b3[t];
}

// ------- LayerNorm + ELU (64-col shard-major input, row-major output), bf16x8 --------
// 2 rows per 256-thread block: threads 0-127 -> row 2b, 128-255 -> row 2b+1.
__global__ __launch_bounds__(256) void ln_elu_k(const __bf16* __restrict__ in,
                                                const float* __restrict__ g,
                                                const float* __restrict__ be,
                                                __bf16* __restrict__ out, int rows_real) {
    const int half = threadIdx.x >> 7;   // 0/1
    const int t = threadIdx.x & 127;     // col-octet 0..127
    const int n = blockIdx.x * 2 + half;
    const size_t ro = (size_t)n * 1024 + t * 8;
    __shared__ float rs[8];
    bf16x8 v8;
    float v[8];
    float s = 0.f, q = 0.f;
    const bool live = (n < rows_real);
    if (live) {
        v8 = *(const bf16x8*)(in + (size_t)(t >> 3) * SHS + (size_t)n * 64 + (t & 7) * 8);
#pragma unroll
        for (int j = 0; j < 8; j++) {
            v[j] = (float)v8[j];
            s += v[j];
            q += v[j] * v[j];
        }
    }
#pragma unroll
    for (int off = 32; off; off >>= 1) {
        s += __shfl_down(s, off);
        q += __shfl_down(q, off);
    }
    int wid = threadIdx.x >> 6;          // 0..3 (2 waves per row)
    if ((threadIdx.x & 63) == 0) { rs[wid] = s; rs[wid + 4] = q; }
    __syncthreads();
    if (!live) {
        bf16x8 z;
#pragma unroll
        for (int j = 0; j < 8; j++) z[j] = (__bf16)0.f;
        *(bf16x8*)(out + ro) = z;
        return;
    }
    int w0 = half * 2;
    s = rs[w0] + rs[w0 + 1];
    q = rs[w0 + 4] + rs[w0 + 5];
    float mu = s * (1.f / 1024.f);
    float var = q * (1.f / 1024.f) - mu * mu;
    float inv = rsqrtf(fmaxf(var, 0.f) + 1e-5f);
    bf16x8 o8;
#pragma unroll
    for (int j = 0; j < 8; j++) {
        int c = t * 8 + j;
        float y = (v[j] - mu) * inv * g[c] + be[c];
        y = y > 0.f ? y : expm1f(y);
        o8[j] = (__bf16)y;
    }
    *(bf16x8*)(out + ro) = o8;
}

extern "C" void kernel_launch(void* const* d_in, const int* in_sizes, int n_in,
                              void* d_out, int out_size, void* d_ws, size_t ws_size,
                              hipStream_t stream) {
    const float* x   = (const float*)d_in[0];
    const int*   ei  = (const int*)d_in[1];
    const float* W1  = (const float*)d_in[2];
    const float* as1 = (const float*)d_in[3];
    const float* ad1 = (const float*)d_in[4];
    const float* b1  = (const float*)d_in[5];
    const float* W2  = (const float*)d_in[6];
    const float* as2 = (const float*)d_in[7];
    const float* ad2 = (const float*)d_in[8];
    const float* b2  = (const float*)d_in[9];
    const float* W3  = (const float*)d_in[10];
    const float* as3 = (const float*)d_in[11];
    const float* ad3 = (const float*)d_in[12];
    const float* b3  = (const float*)d_in[13];
    const float* sW1 = (const float*)d_in[14];
    const float* sb1 = (const float*)d_in[15];
    const float* sW2 = (const float*)d_in[16];
    const float* sb2 = (const float*)d_in[17];
    const float* g1  = (const float*)d_in[18];
    const float* be1 = (const float*)d_in[19];
    const float* g2  = (const float*)d_in[20];
    const float* be2 = (const float*)d_in[21];
    float* out = (float*)d_out;

    const int Nn = 20000;
    const int E = in_sizes[1] / 2;         // 320000
    const int E2 = E + Nn;                 // 340000
    const int Ecap = E2 + 8 * Nn;          // x8-padded CSR capacity (500000)
    const int Mpad = MPAD;                 // 79*256

    char* p = (char*)d_ws;
    auto alloc = [&](size_t bytes) {
        char* r = p;
        p += (bytes + 255) & ~(size_t)255;
        return r;
    };
    __bf16* WTcat1 = (__bf16*)alloc((size_t)2048 * 64 * 2);
    __bf16* WTcat2 = (__bf16*)alloc((size_t)2048 * 1024 * 2);
    __bf16* W3pT   = (__bf16*)alloc((size_t)768 * 1024 * 2);
    __bf16* xp     = (__bf16*)alloc((size_t)Mpad * 64 * 2);
    __bf16* XL     = (__bf16*)alloc((size_t)Mpad * 1024 * 2);   // 16 shards x SHS
    __bf16* SK     = (__bf16*)alloc((size_t)Mpad * 1024 * 2);   // 16 shards x SHS
    __bf16* H1     = (__bf16*)alloc((size_t)Mpad * 1024 * 2);   // row-major (GEMM A)
    float*  asrcb  = (float*)alloc((size_t)Nn * 6 * 4);
    float*  adstb  = (float*)alloc((size_t)Nn * 6 * 4);
    float*  wbuf   = (float*)alloc((size_t)6 * Ecap * 4);
    int*    rowp   = (int*)alloc((size_t)(Nn + 1) * 4);
    int*    cnt    = (int*)alloc((size_t)Nn * 4);
    int*    scsr   = (int*)alloc((size_t)Ecap * 4);
    int*    eiflag = (int*)alloc(256);
    __bf16* part   = SK;   // SK dead by layer 3 (row-major [n][768] partials)
    (void)ws_size; (void)n_in; (void)out_size;

    // ---- prep (1 launch) ----
    prep_k<<<8000, 256, 0, stream>>>(x, W1, sW1, W2, sW2, W3, xp, WTcat1, WTcat2, W3pT, Nn);

    // ---- padded CSR ----
    zero_probe_k<<<(Nn + 255) / 256, 256, 0, stream>>>(ei, cnt, eiflag, Nn);
    hist_k<<<(E2 + 255) / 256, 256, 0, stream>>>(ei, eiflag, cnt, E, Nn);
    scan_k<<<1, 1024, 0, stream>>>(cnt, rowp, Nn);
    (void)hipMemsetAsync(scsr, 0, (size_t)Ecap * 4, stream);          // dummy src = 0
    (void)hipMemsetAsync(wbuf, 0, (size_t)6 * Ecap * 4, stream);      // dummy w = 0
    fill_csr_k<<<(E2 + 255) / 256, 256, 0, stream>>>(ei, eiflag, rowp, cnt, scsr, E, Nn);
    // cnt now holds real degrees

    // ---- layer 1: 50 -> 4x256 concat ----
    gemm256_bt2<<<dim3(8, Mpad / 256), 512, 0, stream>>>(xp, WTcat1, XL, SK, Mpad, 64);
    alpha_k<<<(Nn * 4 * 64) / 256, 256, 0, stream>>>(XL, 4, as1, ad1, asrcb, adstb, Nn, 4, 256);
    attn_k<<<(Nn + 3) / 4, 256, 0, stream>>>(rowp, cnt, scsr, asrcb, adstb, wbuf, Nn, 4, Ecap);
    agg_skip8<<<dim3((Nn + 3) / 4, 16), 256, 0, stream>>>(XL, wbuf, rowp, scsr, b1, sb1, SK, Nn, Ecap);
    ln_elu_k<<<Mpad / 2, 256, 0, stream>>>(SK, g1, be1, H1, Nn);

    // ---- layer 2: 1024 -> 4x256 concat ----
    gemm256_bt2<<<dim3(8, Mpad / 256), 512, 0, stream>>>(H1, WTcat2, XL, SK, Mpad, 1024);
    alpha_k<<<(Nn * 4 * 64) / 256, 256, 0, stream>>>(XL, 4, as2, ad2, asrcb, adstb, Nn, 4, 256);
    attn_k<<<(Nn + 3) / 4, 256, 0, stream>>>(rowp, cnt, scsr, asrcb, adstb, wbuf, Nn, 4, Ecap);
    agg_skip8<<<dim3((Nn + 3) / 4, 16), 256, 0, stream>>>(XL, wbuf, rowp, scsr, b2, sb2, SK, Nn, Ecap);
    ln_elu_k<<<Mpad / 2, 256, 0, stream>>>(SK, g2, be2, H1, Nn);  // H1 := h2

    // ---- layer 3: 1024 -> 6x(121 pad 128), mean over heads ----
    gemm256_bt<<<dim3(3, Mpad / 256), 512, 0, stream>>>(H1, W3pT, XL, Mpad, 768, 1024);
    alpha_k<<<(Nn * 6 * 64) / 256, 256, 0, stream>>>(XL, 2, as3, ad3, asrcb, adstb, Nn, 6, 121);
    attn_k<<<(Nn + 3) / 4, 256, 0, stream>>>(rowp, cnt, scsr, asrcb, adstb, wbuf, Nn, 6, Ecap);
    agg_mean8<<<dim3((Nn + 3) / 4, 12), 256, 0, stream>>>(XL, wbuf, rowp, scsr, part, Nn, Ecap);
    reduce_mean_k<<<Nn, 128, 0, stream>>>(part, b3, out, Nn);
}

// Round 11
// 869.149 us; speedup vs baseline: 1.1716x; 1.1716x over previous
//
#include <hip/hip_runtime.h>
#include <hip/hip_bf16.h>
#include <math.h>

typedef __attribute__((ext_vector_type(8))) __bf16 bf16x8;
typedef __attribute__((ext_vector_type(4))) float f32x4;

#define MPAD 20224
#define SSZ ((size_t)MPAD * 128)   // shard stride for shard-major XL/SK: [shard][row][128]

#if __has_builtin(__builtin_amdgcn_global_load_lds)
#define GLD16(g, l)                                                                      \
    __builtin_amdgcn_global_load_lds(                                                    \
        (const __attribute__((address_space(1))) unsigned int*)(g),                      \
        (__attribute__((address_space(3))) unsigned int*)(l), 16, 0, 0)
#else
// host-pass / fallback: synchronous 16B copy (semantically equivalent)
#define GLD16(g, l) (*(bf16x8*)(l) = *(const bf16x8*)(g))
#endif

#define BAR() asm volatile("s_barrier" ::: "memory")
#define WAITVM(N) asm volatile("s_waitcnt vmcnt(" #N ")" ::: "memory")

// =====================================================================================
// ROUND-4 CONFIGURATION RESTORED (best measured: 750.4 us total; GEMM 104 us,
// 0 bank conflicts, VGPR=100). Rounds 5-10 all regressed:
//  r5 reg-pipeline -> scratch spills; r8 fused-alpha -> +50us/GEMM (shfl+atomics);
//  r9 1D bid&7 XCD pinning -> L2 thrash (+100us agg); r10 64-col shards -> index
//  stream doubled, agg 157us (issue-bound).
// Only retained delta vs r4: bf16x8-vectorized ln_elu_k (G13).
// GEMM: 256x256 8-wave, BK=32, QUAD-buffered LDS.
// T2 fix: write side LINEAR dest + source chunk permuted tt' = tt ^ (((tt>>5)&1)<<1);
// read side offsets XOR'd with ((m16>>3)&1)<<4.
// vmcnt ledger (4 loads per stage): prologue stages tiles 0,1,2 then vmcnt(8) lands
// tile 0. Body t: issue stage(t+3); LOAD_FRAGS(t); MFMA; vmcnt(8) lands stage(t+1).
// Tail: vmcnt(4)/vmcnt(0). Never drains mid-loop.
// =====================================================================================

#define STAGE_T(t_)                                                                      \
    do {                                                                                 \
        __bf16* Ld = lds + (((t_) & 3) * 16384);                                         \
        const __bf16* Ga = Abase + (t_) * 32;                                            \
        const __bf16* Gb = Bbase + (t_) * 32;                                            \
        GLD16(Ga, Ld + tt * 8);                                                          \
        GLD16(Ga + (size_t)128 * K_, Ld + (tt + 512) * 8);                               \
        GLD16(Gb, Ld + 8192 + tt * 8);                                                   \
        GLD16(Gb + (size_t)128 * K_, Ld + 8192 + (tt + 512) * 8);                        \
    } while (0)

#define LOAD_FRAGS(t_)                                                                   \
    {                                                                                    \
        const __bf16* Ar = lds + (((t_) & 3) * 16384) + aoff;                            \
        const __bf16* Br = lds + (((t_) & 3) * 16384) + 8192 + boff;                     \
        _Pragma("unroll") for (int i = 0; i < 8; i++)                                    \
            af[i] = *(const bf16x8*)(Ar + i * 512);                                      \
        _Pragma("unroll") for (int j = 0; j < 4; j++)                                    \
            bf[j] = *(const bf16x8*)(Br + j * 512);                                      \
    }

#define MFMA_ALL()                                                                       \
    __builtin_amdgcn_s_setprio(1);                                                       \
    _Pragma("unroll") for (int i = 0; i < 8; i++)                                        \
        _Pragma("unroll") for (int j = 0; j < 4; j++)                                    \
            acc[i][j] = __builtin_amdgcn_mfma_f32_16x16x32_bf16(af[i], bf[j],            \
                                                                acc[i][j], 0, 0, 0);     \
    __builtin_amdgcn_s_setprio(0);

#define GEMM256_BODY(A, Bt, K_, ...)                                                     \
    __shared__ __align__(16) __bf16 lds[65536];                                          \
    const int tt = threadIdx.x;                                                          \
    const int lane = tt & 63;                                                            \
    const int wid = tt >> 6;                                                             \
    const int wr = wid >> 2; /* 0..1: M half */                                          \
    const int wc = wid & 3;  /* 0..3: N quarter */                                       \
    /* T1: bijective XCD swizzle (m204) so col-tiles sharing an A panel stay on 1 XCD */ \
    const int nwg = gridDim.x * gridDim.y;                                               \
    const int wg0 = blockIdx.y * gridDim.x + blockIdx.x;                                 \
    const int qq = nwg >> 3, rr = nwg & 7, xcd = wg0 & 7, oo = wg0 >> 3;                 \
    const int swz = (xcd < rr ? xcd * (qq + 1) : rr * (qq + 1) + (xcd - rr) * qq) + oo;  \
    const int bm = (swz / gridDim.x) * 256;                                              \
    const int bn = (swz % gridDim.x) * 256;                                              \
    const int m16 = lane & 15;                                                           \
    const int c4 = lane >> 4;                                                            \
    const int NT = K_ >> 5;                                                              \
    const int ttp = tt ^ (((tt >> 5) & 1) << 1); /* pre-swizzled source chunk */         \
    const int srow = ttp >> 2;                                                           \
    const int sch = (ttp & 3) << 3;                                                      \
    const __bf16* Abase = A + (size_t)(bm + srow) * K_ + sch;                            \
    const __bf16* Bbase = Bt + (size_t)(bn + srow) * K_ + sch;                           \
    const int fsw = ((m16 >> 3) & 1) << 4;                                               \
    const int aoff = (((wr * 128 + m16) * 32) + c4 * 8) ^ fsw;                           \
    const int boff = (((wc * 64 + m16) * 32) + c4 * 8) ^ fsw;                            \
    f32x4 acc[8][4];                                                                     \
    _Pragma("unroll") for (int i = 0; i < 8; i++)                                        \
        _Pragma("unroll") for (int j = 0; j < 4; j++)                                    \
            acc[i][j] = (f32x4){0.f, 0.f, 0.f, 0.f};                                     \
    bf16x8 af[8], bf[4];                                                                 \
    /* prologue: stage tiles 0..2; land tile 0; keep {1,2} in flight */                  \
    STAGE_T(0);                                                                          \
    if (NT > 1) STAGE_T(1);                                                              \
    if (NT > 2) STAGE_T(2);                                                              \
    if (NT > 2) { WAITVM(8); } else if (NT > 1) { WAITVM(4); } else { WAITVM(0); }       \
    BAR();                                                                               \
    for (int t = 0; t < NT; t++) {                                                       \
        if (t + 3 < NT) STAGE_T(t + 3);                                                  \
        LOAD_FRAGS(t);                                                                   \
        MFMA_ALL();                                                                      \
        if (t + 1 < NT) {                                                                \
            if (t + 3 < NT) { WAITVM(8); }                                               \
            else if (t + 3 == NT) { WAITVM(4); }                                         \
            else { WAITVM(0); }                                                          \
            BAR();                                                                       \
        }                                                                                \
    }                                                                                    \
    __VA_ARGS__

// Single-output (layer 3): C shard-major [col>>7][row][128], cols < 768
__global__ __launch_bounds__(512, 2) void gemm256_bt(const __bf16* __restrict__ A,
                                                     const __bf16* __restrict__ Bt,
                                                     __bf16* __restrict__ C,
                                                     int M, int N_, int K_) {
    GEMM256_BODY(A, Bt, K_,
        { const int r4 = c4 << 2;
          const int rb = bm + wr * 128;
          _Pragma("unroll") for (int i = 0; i < 8; i++)
              _Pragma("unroll") for (int j = 0; j < 4; j++) {
                  int col = bn + wc * 64 + j * 16 + m16;
                  size_t sb_ = (size_t)(col >> 7) * SSZ + (col & 127);
                  _Pragma("unroll") for (int r = 0; r < 4; r++) {
                      int row = rb + i * 16 + r4 + r;
                      C[sb_ + (size_t)row * 128] = (__bf16)acc[i][j][r];
                  }
              } })
}

// Dual-output: Bt 2048 rows; cols 0-1023 -> C0, 1024-2047 -> C1, both shard-major
__global__ __launch_bounds__(512, 2) void gemm256_bt2(const __bf16* __restrict__ A,
                                                      const __bf16* __restrict__ Bt,
                                                      __bf16* __restrict__ C0,
                                                      __bf16* __restrict__ C1,
                                                      int M, int K_) {
    GEMM256_BODY(A, Bt, K_,
        { const int r4 = c4 << 2;
          const int rb = bm + wr * 128;
          _Pragma("unroll") for (int i = 0; i < 8; i++)
              _Pragma("unroll") for (int j = 0; j < 4; j++) {
                  int col = bn + wc * 64 + j * 16 + m16;
                  __bf16* Cp = (col < 1024) ? C0 : C1;
                  int c10 = col & 1023;
                  size_t sb_ = (size_t)(c10 >> 7) * SSZ + (c10 & 127);
                  _Pragma("unroll") for (int r = 0; r < 4; r++) {
                      int row = rb + i * 16 + r4 + r;
                      Cp[sb_ + (size_t)row * 128] = (__bf16)acc[i][j][r];
                  }
              } })
}

// ---------------- combined prep: pack x + all weight transposes, one launch ----------
__device__ __forceinline__ void transpose_tile(const float* __restrict__ W,
                                               __bf16* __restrict__ WT,
                                               int K, int N, int Kp, int Np,
                                               int bx, int by, float* sm) {
    int tx = threadIdx.x & 31, ty = threadIdx.x >> 5;
#pragma unroll
    for (int r = ty; r < 32; r += 8) {
        int k = by * 32 + r, n = bx * 32 + tx;
        float v = 0.f;
        if (k < K && n < N) v = W[(size_t)k * N + n];
        sm[r * 33 + tx] = v;
    }
    __syncthreads();
#pragma unroll
    for (int r = ty; r < 32; r += 8) {
        int n = bx * 32 + r, k = by * 32 + tx;
        if (n < Np && k < Kp) WT[(size_t)n * Kp + k] = (__bf16)sm[tx * 33 + r];
    }
}

__device__ __forceinline__ void transpose_w3_tile(const float* __restrict__ W,
                                                  __bf16* __restrict__ WT,
                                                  int bx, int by, float* sm) {
    int tx = threadIdx.x & 31, ty = threadIdx.x >> 5;
    int r0 = bx * 32;
    int h = r0 >> 7;
    int c0 = r0 & 127;
#pragma unroll
    for (int r = ty; r < 32; r += 8) {
        int k = by * 32 + r;
        int c = c0 + tx;
        float v = 0.f;
        if (c < 121) v = W[(size_t)k * 726 + h * 121 + c];
        sm[r * 33 + tx] = v;
    }
    __syncthreads();
#pragma unroll
    for (int r = ty; r < 32; r += 8) {
        int rr = r0 + r;
        int k = by * 32 + tx;
        WT[(size_t)rr * 1024 + k] = (__bf16)sm[tx * 33 + r];
    }
}

__global__ __launch_bounds__(256) void prep_k(const float* __restrict__ x,
                                              const float* __restrict__ W1,
                                              const float* __restrict__ sW1,
                                              const float* __restrict__ W2,
                                              const float* __restrict__ sW2,
                                              const float* __restrict__ W3,
                                              __bf16* __restrict__ xp,
                                              __bf16* __restrict__ WTcat1,
                                              __bf16* __restrict__ WTcat2,
                                              __bf16* __restrict__ W3pT, int Nn) {
    __shared__ float sm[32 * 33];
    int b = blockIdx.x;
    if (b < 5056) {                       // xp: 20224 rows x 64 cols
        int i = b * 256 + threadIdx.x;
        int n = i >> 6, c = i & 63;
        float v = 0.f;
        if (n < Nn && c < 50) v = x[n * 50 + c];
        xp[(size_t)n * 64 + c] = (__bf16)v;
    } else if (b < 5120) {
        int i = b - 5056; transpose_tile(W1, WTcat1, 50, 1024, 64, 1024, i % 32, i / 32, sm);
    } else if (b < 5184) {
        int i = b - 5120; transpose_tile(sW1, WTcat1 + 1024 * 64, 50, 1024, 64, 1024, i % 32, i / 32, sm);
    } else if (b < 6208) {
        int i = b - 5184; transpose_tile(W2, WTcat2, 1024, 1024, 1024, 1024, i % 32, i / 32, sm);
    } else if (b < 7232) {
        int i = b - 6208; transpose_tile(sW2, WTcat2 + (size_t)1024 * 1024, 1024, 1024, 1024, 1024, i % 32, i / 32, sm);
    } else {
        int i = b - 7232; transpose_w3_tile(W3, W3pT, i % 24, i / 24, sm);
    }
}

// ---------------- CSR build (by dst, self-loops appended, degree padded to x8) ----------
__global__ void zero_probe_k(const int* __restrict__ ei, int* __restrict__ cnt,
                             int* __restrict__ flag, int Nn) {
    int i = blockIdx.x * 256 + threadIdx.x;
    if (i < Nn) cnt[i] = 0;
    if (blockIdx.x == 0 && threadIdx.x == 0) {
        int all0 = 1;
        for (int k = 0; k < 64; k++)
            if (ei[2 * k + 1] != 0) { all0 = 0; break; }
        *flag = all0;
    }
}

__device__ __forceinline__ int load_ei(const int* ei, int idx, int is64) {
    return is64 ? ei[2 * idx] : ei[idx];
}

__global__ void hist_k(const int* __restrict__ ei, const int* __restrict__ flag,
                       int* __restrict__ cnt, int E, int Nn) {
    int e = blockIdx.x * 256 + threadIdx.x;
    if (e >= E + Nn) return;
    int is64 = *flag;
    int d = (e < E) ? load_ei(ei, E + e, is64) : (e - E);
    d = min(max(d, 0), Nn - 1);
    atomicAdd(&cnt[d], 1);
}

// exclusive scan over x8-PADDED counts; zeros cnt afterwards (cursor for fill)
__global__ __launch_bounds__(1024) void scan_k(int* __restrict__ cnt, int* __restrict__ row_ptr,
                                               int Nn) {
    __shared__ int part[1024];
    int t = threadIdx.x;
    int chunk = (Nn + 1023) >> 10;
    int lo = t * chunk;
    int hi = lo + chunk; if (hi > Nn) hi = Nn; if (lo > Nn) lo = Nn;
    int s = 0;
    for (int i = lo; i < hi; i++) s += (cnt[i] + 7) & ~7;
    part[t] = s;
    __syncthreads();
    for (int off = 1; off < 1024; off <<= 1) {
        int v = (t >= off) ? part[t - off] : 0;
        __syncthreads();
        part[t] += v;
        __syncthreads();
    }
    int run = part[t] - s;
    for (int i = lo; i < hi; i++) { row_ptr[i] = run; run += (cnt[i] + 7) & ~7; }
    if (t == 1023) row_ptr[Nn] = part[1023];
    __syncthreads();
    for (int i = lo; i < hi; i++) cnt[i] = 0;
}

__global__ void fill_csr_k(const int* __restrict__ ei, const int* __restrict__ flag,
                           const int* __restrict__ row_ptr, int* __restrict__ cursor,
                           int* __restrict__ src_csr, int E, int Nn) {
    int e = blockIdx.x * 256 + threadIdx.x;
    if (e >= E + Nn) return;
    int is64 = *flag;
    int d = (e < E) ? load_ei(ei, E + e, is64) : (e - E);
    int s = (e < E) ? load_ei(ei, e, is64) : (e - E);
    d = min(max(d, 0), Nn - 1);
    s = min(max(s, 0), Nn - 1);
    int slot = row_ptr[d] + atomicAdd(&cursor[d], 1);
    src_csr[slot] = s;
}

// ---------------- per-(node,head) attention dots (shard-major XL) ----------------
__global__ void alpha_k(const __bf16* __restrict__ XL, int sph, const float* __restrict__ a_src,
                        const float* __restrict__ a_dst, float* __restrict__ asrc,
                        float* __restrict__ adst, int Nn, int H, int C) {
    int gw = (blockIdx.x * 256 + threadIdx.x) >> 6;
    int lane = threadIdx.x & 63;
    if (gw >= Nn * H) return;
    int n = gw / H, h = gw - n * H;
    const float* as = a_src + h * C;
    const float* ad = a_dst + h * C;
    float s = 0.f, d = 0.f;
    for (int c = lane; c < C; c += 64) {
        float v = (float)XL[(size_t)(h * sph + (c >> 7)) * SSZ + (size_t)n * 128 + (c & 127)];
        s += v * as[c];
        d += v * ad[c];
    }
#pragma unroll
    for (int off = 32; off; off >>= 1) {
        s += __shfl_down(s, off);
        d += __shfl_down(d, off);
    }
    if (lane == 0) { asrc[n * H + h] = s; adst[n * H + h] = d; }
}

// ------- per-node segment softmax -> transposed edge weights wt[h][Ecap] ----------
__global__ void attn_k(const int* __restrict__ row_ptr, const int* __restrict__ deg,
                       const int* __restrict__ src_csr,
                       const float* __restrict__ asrc, const float* __restrict__ adst,
                       float* __restrict__ wt, int Nn, int H, int Ecap) {
    int gw = (blockIdx.x * 256 + threadIdx.x) >> 6;
    int lane = threadIdx.x & 63;
    if (gw >= Nn) return;
    int n = gw;
    int base = row_ptr[n], dg = deg[n];
    if (dg <= 64) {
        // fast path: one edge per lane, single pass
        bool v = lane < dg;
        int src = v ? src_csr[base + lane] : 0;
        for (int h = 0; h < H; h++) {
            float ad = adst[n * H + h];
            float e = -1e30f;
            if (v) {
                e = asrc[src * H + h] + ad;
                e = e > 0.f ? e : 0.2f * e;
            }
            float m = e;
#pragma unroll
            for (int off = 1; off < 64; off <<= 1) m = fmaxf(m, __shfl_xor(m, off));
            float ex = v ? __expf(e - m) : 0.f;
            float sum = ex;
#pragma unroll
            for (int off = 1; off < 64; off <<= 1) sum += __shfl_xor(sum, off);
            if (v) wt[(size_t)h * Ecap + base + lane] = ex / (sum + 1e-16f);
        }
        return;
    }
    for (int h = 0; h < H; h++) {
        float ad = adst[n * H + h];
        float m = -1e30f;
        for (int s = lane; s < dg; s += 64) {
            float e = asrc[src_csr[base + s] * H + h] + ad;
            e = e > 0.f ? e : 0.2f * e;
            m = fmaxf(m, e);
        }
#pragma unroll
        for (int off = 1; off < 64; off <<= 1) m = fmaxf(m, __shfl_xor(m, off));
        float sum = 0.f;
        for (int s = lane; s < dg; s += 64) {
            float e = asrc[src_csr[base + s] * H + h] + ad;
            e = e > 0.f ? e : 0.2f * e;
            sum += __expf(e - m);
        }
#pragma unroll
        for (int off = 1; off < 64; off <<= 1) sum += __shfl_xor(sum, off);
        float inv = 1.f / (sum + 1e-16f);
        float* wrow = wt + (size_t)h * Ecap;
        for (int s = lane; s < dg; s += 64) {
            float e = asrc[src_csr[base + s] * H + h] + ad;
            e = e > 0.f ? e : 0.2f * e;
            wrow[base + s] = __expf(e - m) * inv;
        }
    }
}

// ------- shard-major aggregation, layers 1/2 (8 shards of 128 cols), x8-padded CSR -----
// grid: (nodeBlocks, 8); cc = blockIdx.y so same-shard blocks are temporally clustered
// and the shard slab (MPAD*128*2B = 5.2 MB) stays L2-hot (r4 config, best measured).
__global__ __launch_bounds__(256) void agg_skip8(const __bf16* __restrict__ XL,
                                                 const float* __restrict__ wt,
                                                 const int* __restrict__ row_ptr,
                                                 const int* __restrict__ src_csr,
                                                 const float* __restrict__ bias,
                                                 const float* __restrict__ sb,
                                                 __bf16* __restrict__ SK, int Nn, int Ecap) {
    const int cc = blockIdx.y;                 // 0..7
    const int n = blockIdx.x * 4 + (threadIdx.x >> 6);
    const int lane = threadIdx.x & 63;
    if (n >= Nn) return;
    const int g = lane >> 4;                   // edge group 0..3, 2 contiguous edges each
    const int p = lane & 15;
    const int col = cc * 128 + p * 8;
    const float* wrow = wt + (size_t)(cc >> 1) * Ecap;
    const __bf16* XLc = XL + (size_t)cc * SSZ + p * 8;
    const int base = row_ptr[n], end = row_ptr[n + 1];

    float acc[8];
#pragma unroll
    for (int j = 0; j < 8; j++) acc[j] = 0.f;

    for (int e = base; e < end; e += 8) {
        int2 si = *(const int2*)(src_csr + e + 2 * g);
        float2 wv = *(const float2*)(wrow + e + 2 * g);
        bf16x8 xa = *(const bf16x8*)(XLc + (size_t)si.x * 128);
        bf16x8 xb = *(const bf16x8*)(XLc + (size_t)si.y * 128);
#pragma unroll
        for (int j = 0; j < 8; j++) acc[j] += wv.x * (float)xa[j] + wv.y * (float)xb[j];
    }
#pragma unroll
    for (int j = 0; j < 8; j++) {
        acc[j] += __shfl_xor(acc[j], 16);
        acc[j] += __shfl_xor(acc[j], 32);
    }
    if (lane < 16) {
        size_t o = (size_t)cc * SSZ + (size_t)n * 128 + p * 8;
        bf16x8 sk = *(const bf16x8*)(SK + o);
        bf16x8 res;
#pragma unroll
        for (int j = 0; j < 8; j++)
            res[j] = (__bf16)(acc[j] + bias[col + j] + sb[col + j] + (float)sk[j]);
        *(bf16x8*)(SK + o) = res;
    }
}

// ------- layer-3 aggregation, shard-major xl [6][MPAD][128] -> bf16 partials [n][768] --
__global__ __launch_bounds__(256) void agg_mean8(const __bf16* __restrict__ XL,
                                                 const float* __restrict__ wt,
                                                 const int* __restrict__ row_ptr,
                                                 const int* __restrict__ src_csr,
                                                 __bf16* __restrict__ part, int Nn, int Ecap) {
    const int cc = blockIdx.y;                 // head 0..5
    const int n = blockIdx.x * 4 + (threadIdx.x >> 6);
    const int lane = threadIdx.x & 63;
    if (n >= Nn) return;
    const int g = lane >> 4;
    const int p = lane & 15;
    const int col = cc * 128 + p * 8;
    const float* wrow = wt + (size_t)cc * Ecap;
    const __bf16* XLc = XL + (size_t)cc * SSZ + p * 8;
    const int base = row_ptr[n], end = row_ptr[n + 1];

    float acc[8];
#pragma unroll
    for (int j = 0; j < 8; j++) acc[j] = 0.f;

    for (int e = base; e < end; e += 8) {
        int2 si = *(const int2*)(src_csr + e + 2 * g);
        float2 wv = *(const float2*)(wrow + e + 2 * g);
        bf16x8 xa = *(const bf16x8*)(XLc + (size_t)si.x * 128);
        bf16x8 xb = *(const bf16x8*)(XLc + (size_t)si.y * 128);
#pragma unroll
        for (int j = 0; j < 8; j++) acc[j] += wv.x * (float)xa[j] + wv.y * (float)xb[j];
    }
#pragma unroll
    for (int j = 0; j < 8; j++) {
        acc[j] += __shfl_xor(acc[j], 16);
        acc[j] += __shfl_xor(acc[j], 32);
    }
    if (lane < 16) {
        size_t o = (size_t)n * 768 + col;
        bf16x8 res;
#pragma unroll
        for (int j = 0; j < 8; j++) res[j] = (__bf16)acc[j];
        *(bf16x8*)(part + o) = res;
    }
}

// -------- head-mean over bf16 partials (head stride 128) + bias -> fp32 out --------
__global__ __launch_bounds__(128) void reduce_mean_k(const __bf16* __restrict__ part,
                                                     const float* __restrict__ b3,
                                                     float* __restrict__ out, int Nn) {
    int n = blockIdx.x;
    int t = threadIdx.x;
    if (t >= 121) return;
    const __bf16* row = part + (size_t)n * 768;
    float s = 0.f;
#pragma unroll
    for (int h = 0; h < 6; h++) s += (float)row[h * 128 + t];
    out[(size_t)n * 121 + t] = s * (1.f / 6.f) + b3[t];
}

// ------- LayerNorm + ELU (128-col shard-major input, row-major output), bf16x8 -------
// 2 rows per 256-thread block: threads 0-127 -> row 2b, 128-255 -> row 2b+1.
// One bf16x8 load + one bf16x8 store per thread (G13).
__global__ __launch_bounds__(256) void ln_elu_k(const __bf16* __restrict__ in,
                                                const float* __restrict__ g,
                                                const float* __restrict__ be,
                                                __bf16* __restrict__ out, int rows_real) {
    const int half = threadIdx.x >> 7;   // 0/1
    const int t = threadIdx.x & 127;     // col-octet 0..127
    const int n = blockIdx.x * 2 + half;
    const size_t ro = (size_t)n * 1024 + t * 8;
    __shared__ float rs[8];
    bf16x8 v8;
    float v[8];
    float s = 0.f, q = 0.f;
    const bool live = (n < rows_real);
    if (live) {
        v8 = *(const bf16x8*)(in + (size_t)(t >> 4) * SSZ + (size_t)n * 128 + (t & 15) * 8);
#pragma unroll
        for (int j = 0; j < 8; j++) {
            v[j] = (float)v8[j];
            s += v[j];
            q += v[j] * v[j];
        }
    }
#pragma unroll
    for (int off = 32; off; off >>= 1) {
        s += __shfl_down(s, off);
        q += __shfl_down(q, off);
    }
    int wid = threadIdx.x >> 6;          // 0..3 (2 waves per row)
    if ((threadIdx.x & 63) == 0) { rs[wid] = s; rs[wid + 4] = q; }
    __syncthreads();
    if (!live) {
        bf16x8 z;
#pragma unroll
        for (int j = 0; j < 8; j++) z[j] = (__bf16)0.f;
        *(bf16x8*)(out + ro) = z;
        return;
    }
    int w0 = half * 2;
    s = rs[w0] + rs[w0 + 1];
    q = rs[w0 + 4] + rs[w0 + 5];
    float mu = s * (1.f / 1024.f);
    float var = q * (1.f / 1024.f) - mu * mu;
    float inv = rsqrtf(fmaxf(var, 0.f) + 1e-5f);
    bf16x8 o8;
#pragma unroll
    for (int j = 0; j < 8; j++) {
        int c = t * 8 + j;
        float y = (v[j] - mu) * inv * g[c] + be[c];
        y = y > 0.f ? y : expm1f(y);
        o8[j] = (__bf16)y;
    }
    *(bf16x8*)(out + ro) = o8;
}

extern "C" void kernel_launch(void* const* d_in, const int* in_sizes, int n_in,
                              void* d_out, int out_size, void* d_ws, size_t ws_size,
                              hipStream_t stream) {
    const float* x   = (const float*)d_in[0];
    const int*   ei  = (const int*)d_in[1];
    const float* W1  = (const float*)d_in[2];
    const float* as1 = (const float*)d_in[3];
    const float* ad1 = (const float*)d_in[4];
    const float* b1  = (const float*)d_in[5];
    const float* W2  = (const float*)d_in[6];
    const float* as2 = (const float*)d_in[7];
    const float* ad2 = (const float*)d_in[8];
    const float* b2  = (const float*)d_in[9];
    const float* W3  = (const float*)d_in[10];
    const float* as3 = (const float*)d_in[11];
    const float* ad3 = (const float*)d_in[12];
    const float* b3  = (const float*)d_in[13];
    const float* sW1 = (const float*)d_in[14];
    const float* sb1 = (const float*)d_in[15];
    const float* sW2 = (const float*)d_in[16];
    const float* sb2 = (const float*)d_in[17];
    const float* g1  = (const float*)d_in[18];
    const float* be1 = (const float*)d_in[19];
    const float* g2  = (const float*)d_in[20];
    const float* be2 = (const float*)d_in[21];
    float* out = (float*)d_out;

    const int Nn = 20000;
    const int E = in_sizes[1] / 2;         // 320000
    const int E2 = E + Nn;                 // 340000
    const int Ecap = E2 + 8 * Nn;          // x8-padded CSR capacity (500000)
    const int Mpad = MPAD;                 // 79*256

    char* p = (char*)d_ws;
    auto alloc = [&](size_t bytes) {
        char* r = p;
        p += (bytes + 255) & ~(size_t)255;
        return r;
    };
    __bf16* WTcat1 = (__bf16*)alloc((size_t)2048 * 64 * 2);
    __bf16* WTcat2 = (__bf16*)alloc((size_t)2048 * 1024 * 2);
    __bf16* W3pT   = (__bf16*)alloc((size_t)768 * 1024 * 2);
    __bf16* xp     = (__bf16*)alloc((size_t)Mpad * 64 * 2);
    __bf16* XL     = (__bf16*)alloc((size_t)Mpad * 1024 * 2);   // 8 shards x SSZ
    __bf16* SK     = (__bf16*)alloc((size_t)Mpad * 1024 * 2);   // 8 shards x SSZ
    __bf16* H1     = (__bf16*)alloc((size_t)Mpad * 1024 * 2);   // row-major (GEMM A)
    float*  asrcb  = (float*)alloc((size_t)Nn * 6 * 4);
    float*  adstb  = (float*)alloc((size_t)Nn * 6 * 4);
    float*  wbuf   = (float*)alloc((size_t)6 * Ecap * 4);
    int*    rowp   = (int*)alloc((size_t)(Nn + 1) * 4);
    int*    cnt    = (int*)alloc((size_t)Nn * 4);
    int*    scsr   = (int*)alloc((size_t)Ecap * 4);
    int*    eiflag = (int*)alloc(256);
    __bf16* part   = SK;   // SK dead by layer 3 (row-major [n][768] partials)
    (void)ws_size; (void)n_in; (void)out_size;

    // ---- prep (1 launch) ----
    prep_k<<<8000, 256, 0, stream>>>(x, W1, sW1, W2, sW2, W3, xp, WTcat1, WTcat2, W3pT, Nn);

    // ---- padded CSR ----
    zero_probe_k<<<(Nn + 255) / 256, 256, 0, stream>>>(ei, cnt, eiflag, Nn);
    hist_k<<<(E2 + 255) / 256, 256, 0, stream>>>(ei, eiflag, cnt, E, Nn);
    scan_k<<<1, 1024, 0, stream>>>(cnt, rowp, Nn);
    (void)hipMemsetAsync(scsr, 0, (size_t)Ecap * 4, stream);          // dummy src = 0
    (void)hipMemsetAsync(wbuf, 0, (size_t)6 * Ecap * 4, stream);      // dummy w = 0
    fill_csr_k<<<(E2 + 255) / 256, 256, 0, stream>>>(ei, eiflag, rowp, cnt, scsr, E, Nn);
    // cnt now holds real degrees

    // ---- layer 1: 50 -> 4x256 concat ----
    gemm256_bt2<<<dim3(8, Mpad / 256), 512, 0, stream>>>(xp, WTcat1, XL, SK, Mpad, 64);
    alpha_k<<<(Nn * 4 * 64) / 256, 256, 0, stream>>>(XL, 2, as1, ad1, asrcb, adstb, Nn, 4, 256);
    attn_k<<<(Nn + 3) / 4, 256, 0, stream>>>(rowp, cnt, scsr, asrcb, adstb, wbuf, Nn, 4, Ecap);
    agg_skip8<<<dim3((Nn + 3) / 4, 8), 256, 0, stream>>>(XL, wbuf, rowp, scsr, b1, sb1, SK, Nn, Ecap);
    ln_elu_k<<<Mpad / 2, 256, 0, stream>>>(SK, g1, be1, H1, Nn);

    // ---- layer 2: 1024 -> 4x256 concat ----
    gemm256_bt2<<<dim3(8, Mpad / 256), 512, 0, stream>>>(H1, WTcat2, XL, SK, Mpad, 1024);
    alpha_k<<<(Nn * 4 * 64) / 256, 256, 0, stream>>>(XL, 2, as2, ad2, asrcb, adstb, Nn, 4, 256);
    attn_k<<<(Nn + 3) / 4, 256, 0, stream>>>(rowp, cnt, scsr, asrcb, adstb, wbuf, Nn, 4, Ecap);
    agg_skip8<<<dim3((Nn + 3) / 4, 8), 256, 0, stream>>>(XL, wbuf, rowp, scsr, b2, sb2, SK, Nn, Ecap);
    ln_elu_k<<<Mpad / 2, 256, 0, stream>>>(SK, g2, be2, H1, Nn);  // H1 := h2

    // ---- layer 3: 1024 -> 6x(121 pad 128), mean over heads ----
    gemm256_bt<<<dim3(3, Mpad / 256), 512, 0, stream>>>(H1, W3pT, XL, Mpad, 768, 1024);
    alpha_k<<<(Nn * 6 * 64) / 256, 256, 0, stream>>>(XL, 1, as3, ad3, asrcb, adstb, Nn, 6, 121);
    attn_k<<<(Nn + 3) / 4, 256, 0, stream>>>(rowp, cnt, scsr, asrcb, adstb, wbuf, Nn, 6, Ecap);
    agg_mean8<<<dim3((Nn + 3) / 4, 6), 256, 0, stream>>>(XL, wbuf, rowp, scsr, part, Nn, Ecap);
    reduce_mean_k<<<Nn, 128, 0, stream>>>(part, b3, out, Nn);
}

// Round 12
// 747.508 us; speedup vs baseline: 1.3623x; 1.1627x over previous
//
#include <hip/hip_runtime.h>
#include <hip/hip_bf16.h>
#include <math.h>

typedef __attribute__((ext_vector_type(8))) __bf16 bf16x8;
typedef __attribute__((ext_vector_type(4))) float f32x4;

#define MPAD 20224
#define SSZ ((size_t)MPAD * 128)   // shard stride for shard-major XL/SK: [shard][row][128]

#if __has_builtin(__builtin_amdgcn_global_load_lds)
#define GLD16(g, l)                                                                      \
    __builtin_amdgcn_global_load_lds(                                                    \
        (const __attribute__((address_space(1))) unsigned int*)(g),                      \
        (__attribute__((address_space(3))) unsigned int*)(l), 16, 0, 0)
#else
// host-pass / fallback: synchronous 16B copy (semantically equivalent)
#define GLD16(g, l) (*(bf16x8*)(l) = *(const bf16x8*)(g))
#endif

#define BAR() asm volatile("s_barrier" ::: "memory")
#define WAITVM(N) asm volatile("s_waitcnt vmcnt(" #N ")" ::: "memory")

// =====================================================================================
// EXACT ROUND-4 KERNEL (best measured: 750.4 us total; GEMM 104 us, 0 bank conflicts,
// VGPR=100, acc in AGPRs). Resubmitted byte-for-byte to isolate container variance
// (r11: identical GEMM code ran 5% slower with 5% lower hbm_gbps -> slow container).
// GEMM: 256x256 8-wave, BK=32, QUAD-buffered LDS, AITER-shape K-loop:
//   ~32 MFMA per barrier, ONE barrier + ONE counted vmcnt per K-tile, 3-tile prefetch.
// T2 fix: write side LINEAR dest + source chunk permuted tt' = tt ^ (((tt>>5)&1)<<1);
// read side offsets XOR'd with ((m16>>3)&1)<<4.
// vmcnt ledger (4 loads per stage): prologue stages tiles 0,1,2 then vmcnt(8) lands
// tile 0. Body t: issue stage(t+3); LOAD_FRAGS(t); MFMA; vmcnt(8) lands stage(t+1).
// Tail: vmcnt(4)/vmcnt(0). Never drains mid-loop.
// =====================================================================================

#define STAGE_T(t_)                                                                      \
    do {                                                                                 \
        __bf16* Ld = lds + (((t_) & 3) * 16384);                                         \
        const __bf16* Ga = Abase + (t_) * 32;                                            \
        const __bf16* Gb = Bbase + (t_) * 32;                                            \
        GLD16(Ga, Ld + tt * 8);                                                          \
        GLD16(Ga + (size_t)128 * K_, Ld + (tt + 512) * 8);                               \
        GLD16(Gb, Ld + 8192 + tt * 8);                                                   \
        GLD16(Gb + (size_t)128 * K_, Ld + 8192 + (tt + 512) * 8);                        \
    } while (0)

#define LOAD_FRAGS(t_)                                                                   \
    {                                                                                    \
        const __bf16* Ar = lds + (((t_) & 3) * 16384) + aoff;                            \
        const __bf16* Br = lds + (((t_) & 3) * 16384) + 8192 + boff;                     \
        _Pragma("unroll") for (int i = 0; i < 8; i++)                                    \
            af[i] = *(const bf16x8*)(Ar + i * 512);                                      \
        _Pragma("unroll") for (int j = 0; j < 4; j++)                                    \
            bf[j] = *(const bf16x8*)(Br + j * 512);                                      \
    }

#define MFMA_ALL()                                                                       \
    __builtin_amdgcn_s_setprio(1);                                                       \
    _Pragma("unroll") for (int i = 0; i < 8; i++)                                        \
        _Pragma("unroll") for (int j = 0; j < 4; j++)                                    \
            acc[i][j] = __builtin_amdgcn_mfma_f32_16x16x32_bf16(af[i], bf[j],            \
                                                                acc[i][j], 0, 0, 0);     \
    __builtin_amdgcn_s_setprio(0);

#define GEMM256_BODY(A, Bt, K_, ...)                                                     \
    __shared__ __align__(16) __bf16 lds[65536];                                          \
    const int tt = threadIdx.x;                                                          \
    const int lane = tt & 63;                                                            \
    const int wid = tt >> 6;                                                             \
    const int wr = wid >> 2; /* 0..1: M half */                                          \
    const int wc = wid & 3;  /* 0..3: N quarter */                                       \
    /* T1: bijective XCD swizzle (m204) so col-tiles sharing an A panel stay on 1 XCD */ \
    const int nwg = gridDim.x * gridDim.y;                                               \
    const int wg0 = blockIdx.y * gridDim.x + blockIdx.x;                                 \
    const int qq = nwg >> 3, rr = nwg & 7, xcd = wg0 & 7, oo = wg0 >> 3;                 \
    const int swz = (xcd < rr ? xcd * (qq + 1) : rr * (qq + 1) + (xcd - rr) * qq) + oo;  \
    const int bm = (swz / gridDim.x) * 256;                                              \
    const int bn = (swz % gridDim.x) * 256;                                              \
    const int m16 = lane & 15;                                                           \
    const int c4 = lane >> 4;                                                            \
    const int NT = K_ >> 5;                                                              \
    const int ttp = tt ^ (((tt >> 5) & 1) << 1); /* pre-swizzled source chunk */         \
    const int srow = ttp >> 2;                                                           \
    const int sch = (ttp & 3) << 3;                                                      \
    const __bf16* Abase = A + (size_t)(bm + srow) * K_ + sch;                            \
    const __bf16* Bbase = Bt + (size_t)(bn + srow) * K_ + sch;                           \
    const int fsw = ((m16 >> 3) & 1) << 4;                                               \
    const int aoff = (((wr * 128 + m16) * 32) + c4 * 8) ^ fsw;                           \
    const int boff = (((wc * 64 + m16) * 32) + c4 * 8) ^ fsw;                            \
    f32x4 acc[8][4];                                                                     \
    _Pragma("unroll") for (int i = 0; i < 8; i++)                                        \
        _Pragma("unroll") for (int j = 0; j < 4; j++)                                    \
            acc[i][j] = (f32x4){0.f, 0.f, 0.f, 0.f};                                     \
    bf16x8 af[8], bf[4];                                                                 \
    /* prologue: stage tiles 0..2; land tile 0; keep {1,2} in flight */                  \
    STAGE_T(0);                                                                          \
    if (NT > 1) STAGE_T(1);                                                              \
    if (NT > 2) STAGE_T(2);                                                              \
    if (NT > 2) { WAITVM(8); } else if (NT > 1) { WAITVM(4); } else { WAITVM(0); }       \
    BAR();                                                                               \
    for (int t = 0; t < NT; t++) {                                                       \
        if (t + 3 < NT) STAGE_T(t + 3);                                                  \
        LOAD_FRAGS(t);                                                                   \
        MFMA_ALL();                                                                      \
        if (t + 1 < NT) {                                                                \
            if (t + 3 < NT) { WAITVM(8); }                                               \
            else if (t + 3 == NT) { WAITVM(4); }                                         \
            else { WAITVM(0); }                                                          \
            BAR();                                                                       \
        }                                                                                \
    }                                                                                    \
    __VA_ARGS__

// Single-output (layer 3): C shard-major [col>>7][row][128], cols < 768
__global__ __launch_bounds__(512, 2) void gemm256_bt(const __bf16* __restrict__ A,
                                                     const __bf16* __restrict__ Bt,
                                                     __bf16* __restrict__ C,
                                                     int M, int N_, int K_) {
    GEMM256_BODY(A, Bt, K_,
        { const int r4 = c4 << 2;
          const int rb = bm + wr * 128;
          _Pragma("unroll") for (int i = 0; i < 8; i++)
              _Pragma("unroll") for (int j = 0; j < 4; j++) {
                  int col = bn + wc * 64 + j * 16 + m16;
                  size_t sb_ = (size_t)(col >> 7) * SSZ + (col & 127);
                  _Pragma("unroll") for (int r = 0; r < 4; r++) {
                      int row = rb + i * 16 + r4 + r;
                      C[sb_ + (size_t)row * 128] = (__bf16)acc[i][j][r];
                  }
              } })
}

// Dual-output: Bt 2048 rows; cols 0-1023 -> C0, 1024-2047 -> C1, both shard-major
__global__ __launch_bounds__(512, 2) void gemm256_bt2(const __bf16* __restrict__ A,
                                                      const __bf16* __restrict__ Bt,
                                                      __bf16* __restrict__ C0,
                                                      __bf16* __restrict__ C1,
                                                      int M, int K_) {
    GEMM256_BODY(A, Bt, K_,
        { const int r4 = c4 << 2;
          const int rb = bm + wr * 128;
          _Pragma("unroll") for (int i = 0; i < 8; i++)
              _Pragma("unroll") for (int j = 0; j < 4; j++) {
                  int col = bn + wc * 64 + j * 16 + m16;
                  __bf16* Cp = (col < 1024) ? C0 : C1;
                  int c10 = col & 1023;
                  size_t sb_ = (size_t)(c10 >> 7) * SSZ + (c10 & 127);
                  _Pragma("unroll") for (int r = 0; r < 4; r++) {
                      int row = rb + i * 16 + r4 + r;
                      Cp[sb_ + (size_t)row * 128] = (__bf16)acc[i][j][r];
                  }
              } })
}

// ---------------- combined prep: pack x + all weight transposes, one launch ----------
__device__ __forceinline__ void transpose_tile(const float* __restrict__ W,
                                               __bf16* __restrict__ WT,
                                               int K, int N, int Kp, int Np,
                                               int bx, int by, float* sm) {
    int tx = threadIdx.x & 31, ty = threadIdx.x >> 5;
#pragma unroll
    for (int r = ty; r < 32; r += 8) {
        int k = by * 32 + r, n = bx * 32 + tx;
        float v = 0.f;
        if (k < K && n < N) v = W[(size_t)k * N + n];
        sm[r * 33 + tx] = v;
    }
    __syncthreads();
#pragma unroll
    for (int r = ty; r < 32; r += 8) {
        int n = bx * 32 + r, k = by * 32 + tx;
        if (n < Np && k < Kp) WT[(size_t)n * Kp + k] = (__bf16)sm[tx * 33 + r];
    }
}

__device__ __forceinline__ void transpose_w3_tile(const float* __restrict__ W,
                                                  __bf16* __restrict__ WT,
                                                  int bx, int by, float* sm) {
    int tx = threadIdx.x & 31, ty = threadIdx.x >> 5;
    int r0 = bx * 32;
    int h = r0 >> 7;
    int c0 = r0 & 127;
#pragma unroll
    for (int r = ty; r < 32; r += 8) {
        int k = by * 32 + r;
        int c = c0 + tx;
        float v = 0.f;
        if (c < 121) v = W[(size_t)k * 726 + h * 121 + c];
        sm[r * 33 + tx] = v;
    }
    __syncthreads();
#pragma unroll
    for (int r = ty; r < 32; r += 8) {
        int rr = r0 + r;
        int k = by * 32 + tx;
        WT[(size_t)rr * 1024 + k] = (__bf16)sm[tx * 33 + r];
    }
}

__global__ __launch_bounds__(256) void prep_k(const float* __restrict__ x,
                                              const float* __restrict__ W1,
                                              const float* __restrict__ sW1,
                                              const float* __restrict__ W2,
                                              const float* __restrict__ sW2,
                                              const float* __restrict__ W3,
                                              __bf16* __restrict__ xp,
                                              __bf16* __restrict__ WTcat1,
                                              __bf16* __restrict__ WTcat2,
                                              __bf16* __restrict__ W3pT, int Nn) {
    __shared__ float sm[32 * 33];
    int b = blockIdx.x;
    if (b < 5056) {                       // xp: 20224 rows x 64 cols
        int i = b * 256 + threadIdx.x;
        int n = i >> 6, c = i & 63;
        float v = 0.f;
        if (n < Nn && c < 50) v = x[n * 50 + c];
        xp[(size_t)n * 64 + c] = (__bf16)v;
    } else if (b < 5120) {
        int i = b - 5056; transpose_tile(W1, WTcat1, 50, 1024, 64, 1024, i % 32, i / 32, sm);
    } else if (b < 5184) {
        int i = b - 5120; transpose_tile(sW1, WTcat1 + 1024 * 64, 50, 1024, 64, 1024, i % 32, i / 32, sm);
    } else if (b < 6208) {
        int i = b - 5184; transpose_tile(W2, WTcat2, 1024, 1024, 1024, 1024, i % 32, i / 32, sm);
    } else if (b < 7232) {
        int i = b - 6208; transpose_tile(sW2, WTcat2 + (size_t)1024 * 1024, 1024, 1024, 1024, 1024, i % 32, i / 32, sm);
    } else {
        int i = b - 7232; transpose_w3_tile(W3, W3pT, i % 24, i / 24, sm);
    }
}

// ---------------- CSR build (by dst, self-loops appended, degree padded to x8) ----------
__global__ void zero_probe_k(const int* __restrict__ ei, int* __restrict__ cnt,
                             int* __restrict__ flag, int Nn) {
    int i = blockIdx.x * 256 + threadIdx.x;
    if (i < Nn) cnt[i] = 0;
    if (blockIdx.x == 0 && threadIdx.x == 0) {
        int all0 = 1;
        for (int k = 0; k < 64; k++)
            if (ei[2 * k + 1] != 0) { all0 = 0; break; }
        *flag = all0;
    }
}

__device__ __forceinline__ int load_ei(const int* ei, int idx, int is64) {
    return is64 ? ei[2 * idx] : ei[idx];
}

__global__ void hist_k(const int* __restrict__ ei, const int* __restrict__ flag,
                       int* __restrict__ cnt, int E, int Nn) {
    int e = blockIdx.x * 256 + threadIdx.x;
    if (e >= E + Nn) return;
    int is64 = *flag;
    int d = (e < E) ? load_ei(ei, E + e, is64) : (e - E);
    d = min(max(d, 0), Nn - 1);
    atomicAdd(&cnt[d], 1);
}

// exclusive scan over x8-PADDED counts; zeros cnt afterwards (cursor for fill)
__global__ __launch_bounds__(1024) void scan_k(int* __restrict__ cnt, int* __restrict__ row_ptr,
                                               int Nn) {
    __shared__ int part[1024];
    int t = threadIdx.x;
    int chunk = (Nn + 1023) >> 10;
    int lo = t * chunk;
    int hi = lo + chunk; if (hi > Nn) hi = Nn; if (lo > Nn) lo = Nn;
    int s = 0;
    for (int i = lo; i < hi; i++) s += (cnt[i] + 7) & ~7;
    part[t] = s;
    __syncthreads();
    for (int off = 1; off < 1024; off <<= 1) {
        int v = (t >= off) ? part[t - off] : 0;
        __syncthreads();
        part[t] += v;
        __syncthreads();
    }
    int run = part[t] - s;
    for (int i = lo; i < hi; i++) { row_ptr[i] = run; run += (cnt[i] + 7) & ~7; }
    if (t == 1023) row_ptr[Nn] = part[1023];
    __syncthreads();
    for (int i = lo; i < hi; i++) cnt[i] = 0;
}

__global__ void fill_csr_k(const int* __restrict__ ei, const int* __restrict__ flag,
                           const int* __restrict__ row_ptr, int* __restrict__ cursor,
                           int* __restrict__ src_csr, int E, int Nn) {
    int e = blockIdx.x * 256 + threadIdx.x;
    if (e >= E + Nn) return;
    int is64 = *flag;
    int d = (e < E) ? load_ei(ei, E + e, is64) : (e - E);
    int s = (e < E) ? load_ei(ei, e, is64) : (e - E);
    d = min(max(d, 0), Nn - 1);
    s = min(max(s, 0), Nn - 1);
    int slot = row_ptr[d] + atomicAdd(&cursor[d], 1);
    src_csr[slot] = s;
}

// ---------------- per-(node,head) attention dots (shard-major XL) ----------------
__global__ void alpha_k(const __bf16* __restrict__ XL, int sph, const float* __restrict__ a_src,
                        const float* __restrict__ a_dst, float* __restrict__ asrc,
                        float* __restrict__ adst, int Nn, int H, int C) {
    int gw = (blockIdx.x * 256 + threadIdx.x) >> 6;
    int lane = threadIdx.x & 63;
    if (gw >= Nn * H) return;
    int n = gw / H, h = gw - n * H;
    const float* as = a_src + h * C;
    const float* ad = a_dst + h * C;
    float s = 0.f, d = 0.f;
    for (int c = lane; c < C; c += 64) {
        float v = (float)XL[(size_t)(h * sph + (c >> 7)) * SSZ + (size_t)n * 128 + (c & 127)];
        s += v * as[c];
        d += v * ad[c];
    }
#pragma unroll
    for (int off = 32; off; off >>= 1) {
        s += __shfl_down(s, off);
        d += __shfl_down(d, off);
    }
    if (lane == 0) { asrc[n * H + h] = s; adst[n * H + h] = d; }
}

// ------- per-node segment softmax -> transposed edge weights wt[h][Ecap] ----------
__global__ void attn_k(const int* __restrict__ row_ptr, const int* __restrict__ deg,
                       const int* __restrict__ src_csr,
                       const float* __restrict__ asrc, const float* __restrict__ adst,
                       float* __restrict__ wt, int Nn, int H, int Ecap) {
    int gw = (blockIdx.x * 256 + threadIdx.x) >> 6;
    int lane = threadIdx.x & 63;
    if (gw >= Nn) return;
    int n = gw;
    int base = row_ptr[n], dg = deg[n];
    if (dg <= 64) {
        // fast path: one edge per lane, single pass
        bool v = lane < dg;
        int src = v ? src_csr[base + lane] : 0;
        for (int h = 0; h < H; h++) {
            float ad = adst[n * H + h];
            float e = -1e30f;
            if (v) {
                e = asrc[src * H + h] + ad;
                e = e > 0.f ? e : 0.2f * e;
            }
            float m = e;
#pragma unroll
            for (int off = 1; off < 64; off <<= 1) m = fmaxf(m, __shfl_xor(m, off));
            float ex = v ? __expf(e - m) : 0.f;
            float sum = ex;
#pragma unroll
            for (int off = 1; off < 64; off <<= 1) sum += __shfl_xor(sum, off);
            if (v) wt[(size_t)h * Ecap + base + lane] = ex / (sum + 1e-16f);
        }
        return;
    }
    for (int h = 0; h < H; h++) {
        float ad = adst[n * H + h];
        float m = -1e30f;
        for (int s = lane; s < dg; s += 64) {
            float e = asrc[src_csr[base + s] * H + h] + ad;
            e = e > 0.f ? e : 0.2f * e;
            m = fmaxf(m, e);
        }
#pragma unroll
        for (int off = 1; off < 64; off <<= 1) m = fmaxf(m, __shfl_xor(m, off));
        float sum = 0.f;
        for (int s = lane; s < dg; s += 64) {
            float e = asrc[src_csr[base + s] * H + h] + ad;
            e = e > 0.f ? e : 0.2f * e;
            sum += __expf(e - m);
        }
#pragma unroll
        for (int off = 1; off < 64; off <<= 1) sum += __shfl_xor(sum, off);
        float inv = 1.f / (sum + 1e-16f);
        float* wrow = wt + (size_t)h * Ecap;
        for (int s = lane; s < dg; s += 64) {
            float e = asrc[src_csr[base + s] * H + h] + ad;
            e = e > 0.f ? e : 0.2f * e;
            wrow[base + s] = __expf(e - m) * inv;
        }
    }
}

// ------- shard-major aggregation, layers 1/2 (8 shards of 128 cols), x8-padded CSR -----
// grid: (nodeBlocks, 8); cc = blockIdx.y so same-shard blocks are temporally clustered
// and the shard slab (MPAD*128*2B = 5.2 MB) stays L2-hot.
__global__ __launch_bounds__(256) void agg_skip8(const __bf16* __restrict__ XL,
                                                 const float* __restrict__ wt,
                                                 const int* __restrict__ row_ptr,
                                                 const int* __restrict__ src_csr,
                                                 const float* __restrict__ bias,
                                                 const float* __restrict__ sb,
                                                 __bf16* __restrict__ SK, int Nn, int Ecap) {
    const int cc = blockIdx.y;                 // 0..7
    const int n = blockIdx.x * 4 + (threadIdx.x >> 6);
    const int lane = threadIdx.x & 63;
    if (n >= Nn) return;
    const int g = lane >> 4;                   // edge group 0..3, 2 contiguous edges each
    const int p = lane & 15;
    const int col = cc * 128 + p * 8;
    const float* wrow = wt + (size_t)(cc >> 1) * Ecap;
    const __bf16* XLc = XL + (size_t)cc * SSZ + p * 8;
    const int base = row_ptr[n], end = row_ptr[n + 1];

    float acc[8];
#pragma unroll
    for (int j = 0; j < 8; j++) acc[j] = 0.f;

    for (int e = base; e < end; e += 8) {
        int2 si = *(const int2*)(src_csr + e + 2 * g);
        float2 wv = *(const float2*)(wrow + e + 2 * g);
        bf16x8 xa = *(const bf16x8*)(XLc + (size_t)si.x * 128);
        bf16x8 xb = *(const bf16x8*)(XLc + (size_t)si.y * 128);
#pragma unroll
        for (int j = 0; j < 8; j++) acc[j] += wv.x * (float)xa[j] + wv.y * (float)xb[j];
    }
#pragma unroll
    for (int j = 0; j < 8; j++) {
        acc[j] += __shfl_xor(acc[j], 16);
        acc[j] += __shfl_xor(acc[j], 32);
    }
    if (lane < 16) {
        size_t o = (size_t)cc * SSZ + (size_t)n * 128 + p * 8;
        bf16x8 sk = *(const bf16x8*)(SK + o);
        bf16x8 res;
#pragma unroll
        for (int j = 0; j < 8; j++)
            res[j] = (__bf16)(acc[j] + bias[col + j] + sb[col + j] + (float)sk[j]);
        *(bf16x8*)(SK + o) = res;
    }
}

// ------- layer-3 aggregation, shard-major xl [6][MPAD][128] -> bf16 partials [n][768] --
__global__ __launch_bounds__(256) void agg_mean8(const __bf16* __restrict__ XL,
                                                 const float* __restrict__ wt,
                                                 const int* __restrict__ row_ptr,
                                                 const int* __restrict__ src_csr,
                                                 __bf16* __restrict__ part, int Nn, int Ecap) {
    const int cc = blockIdx.y;                 // head 0..5
    const int n = blockIdx.x * 4 + (threadIdx.x >> 6);
    const int lane = threadIdx.x & 63;
    if (n >= Nn) return;
    const int g = lane >> 4;
    const int p = lane & 15;
    const int col = cc * 128 + p * 8;
    const float* wrow = wt + (size_t)cc * Ecap;
    const __bf16* XLc = XL + (size_t)cc * SSZ + p * 8;
    const int base = row_ptr[n], end = row_ptr[n + 1];

    float acc[8];
#pragma unroll
    for (int j = 0; j < 8; j++) acc[j] = 0.f;

    for (int e = base; e < end; e += 8) {
        int2 si = *(const int2*)(src_csr + e + 2 * g);
        float2 wv = *(const float2*)(wrow + e + 2 * g);
        bf16x8 xa = *(const bf16x8*)(XLc + (size_t)si.x * 128);
        bf16x8 xb = *(const bf16x8*)(XLc + (size_t)si.y * 128);
#pragma unroll
        for (int j = 0; j < 8; j++) acc[j] += wv.x * (float)xa[j] + wv.y * (float)xb[j];
    }
#pragma unroll
    for (int j = 0; j < 8; j++) {
        acc[j] += __shfl_xor(acc[j], 16);
        acc[j] += __shfl_xor(acc[j], 32);
    }
    if (lane < 16) {
        size_t o = (size_t)n * 768 + col;
        bf16x8 res;
#pragma unroll
        for (int j = 0; j < 8; j++) res[j] = (__bf16)acc[j];
        *(bf16x8*)(part + o) = res;
    }
}

// -------- head-mean over bf16 partials (head stride 128) + bias -> fp32 out --------
__global__ __launch_bounds__(128) void reduce_mean_k(const __bf16* __restrict__ part,
                                                     const float* __restrict__ b3,
                                                     float* __restrict__ out, int Nn) {
    int n = blockIdx.x;
    int t = threadIdx.x;
    if (t >= 121) return;
    const __bf16* row = part + (size_t)n * 768;
    float s = 0.f;
#pragma unroll
    for (int h = 0; h < 6; h++) s += (float)row[h * 128 + t];
    out[(size_t)n * 121 + t] = s * (1.f / 6.f) + b3[t];
}

// ---------------- LayerNorm + ELU (shard-major input, row-major output) ----------------
__global__ __launch_bounds__(256) void ln_elu_k(const __bf16* __restrict__ in,
                                                const float* __restrict__ g,
                                                const float* __restrict__ be,
                                                __bf16* __restrict__ out, int rows_real) {
    const int D = 1024;
    int n = blockIdx.x;
    int t = threadIdx.x;
    size_t ro = (size_t)n * D;
    if (n >= rows_real) {
#pragma unroll
        for (int j = 0; j < 4; j++) out[ro + t + 256 * j] = (__bf16)0.f;
        return;
    }
    float v[4];
    float s = 0.f, q = 0.f;
#pragma unroll
    for (int j = 0; j < 4; j++) {
        int c = t + 256 * j;
        float a = (float)in[(size_t)(c >> 7) * SSZ + (size_t)n * 128 + (c & 127)];
        v[j] = a;
        s += a;
        q += a * a;
    }
#pragma unroll
    for (int off = 32; off; off >>= 1) {
        s += __shfl_down(s, off);
        q += __shfl_down(q, off);
    }
    __shared__ float rs[8];
    int wid = t >> 6;
    if ((t & 63) == 0) { rs[wid] = s; rs[wid + 4] = q; }
    __syncthreads();
    s = rs[0] + rs[1] + rs[2] + rs[3];
    q = rs[4] + rs[5] + rs[6] + rs[7];
    float mu = s * (1.f / 1024.f);
    float var = q * (1.f / 1024.f) - mu * mu;
    float inv = rsqrtf(fmaxf(var, 0.f) + 1e-5f);
#pragma unroll
    for (int j = 0; j < 4; j++) {
        int c = t + 256 * j;
        float y = (v[j] - mu) * inv * g[c] + be[c];
        y = y > 0.f ? y : expm1f(y);
        out[ro + c] = (__bf16)y;
    }
}

extern "C" void kernel_launch(void* const* d_in, const int* in_sizes, int n_in,
                              void* d_out, int out_size, void* d_ws, size_t ws_size,
                              hipStream_t stream) {
    const float* x   = (const float*)d_in[0];
    const int*   ei  = (const int*)d_in[1];
    const float* W1  = (const float*)d_in[2];
    const float* as1 = (const float*)d_in[3];
    const float* ad1 = (const float*)d_in[4];
    const float* b1  = (const float*)d_in[5];
    const float* W2  = (const float*)d_in[6];
    const float* as2 = (const float*)d_in[7];
    const float* ad2 = (const float*)d_in[8];
    const float* b2  = (const float*)d_in[9];
    const float* W3  = (const float*)d_in[10];
    const float* as3 = (const float*)d_in[11];
    const float* ad3 = (const float*)d_in[12];
    const float* b3  = (const float*)d_in[13];
    const float* sW1 = (const float*)d_in[14];
    const float* sb1 = (const float*)d_in[15];
    const float* sW2 = (const float*)d_in[16];
    const float* sb2 = (const float*)d_in[17];
    const float* g1  = (const float*)d_in[18];
    const float* be1 = (const float*)d_in[19];
    const float* g2  = (const float*)d_in[20];
    const float* be2 = (const float*)d_in[21];
    float* out = (float*)d_out;

    const int Nn = 20000;
    const int E = in_sizes[1] / 2;         // 320000
    const int E2 = E + Nn;                 // 340000
    const int Ecap = E2 + 8 * Nn;          // x8-padded CSR capacity (500000)
    const int Mpad = MPAD;                 // 79*256

    char* p = (char*)d_ws;
    auto alloc = [&](size_t bytes) {
        char* r = p;
        p += (bytes + 255) & ~(size_t)255;
        return r;
    };
    __bf16* WTcat1 = (__bf16*)alloc((size_t)2048 * 64 * 2);
    __bf16* WTcat2 = (__bf16*)alloc((size_t)2048 * 1024 * 2);
    __bf16* W3pT   = (__bf16*)alloc((size_t)768 * 1024 * 2);
    __bf16* xp     = (__bf16*)alloc((size_t)Mpad * 64 * 2);
    __bf16* XL     = (__bf16*)alloc((size_t)Mpad * 1024 * 2);   // 8 shards x SSZ
    __bf16* SK     = (__bf16*)alloc((size_t)Mpad * 1024 * 2);   // 8 shards x SSZ
    __bf16* H1     = (__bf16*)alloc((size_t)Mpad * 1024 * 2);   // row-major (GEMM A)
    float*  asrcb  = (float*)alloc((size_t)Nn * 6 * 4);
    float*  adstb  = (float*)alloc((size_t)Nn * 6 * 4);
    float*  wbuf   = (float*)alloc((size_t)6 * Ecap * 4);
    int*    rowp   = (int*)alloc((size_t)(Nn + 1) * 4);
    int*    cnt    = (int*)alloc((size_t)Nn * 4);
    int*    scsr   = (int*)alloc((size_t)Ecap * 4);
    int*    eiflag = (int*)alloc(256);
    __bf16* part   = SK;   // SK dead by layer 3 (row-major [n][768] partials)
    (void)ws_size; (void)n_in; (void)out_size;

    // ---- prep (1 launch) ----
    prep_k<<<8000, 256, 0, stream>>>(x, W1, sW1, W2, sW2, W3, xp, WTcat1, WTcat2, W3pT, Nn);

    // ---- padded CSR ----
    zero_probe_k<<<(Nn + 255) / 256, 256, 0, stream>>>(ei, cnt, eiflag, Nn);
    hist_k<<<(E2 + 255) / 256, 256, 0, stream>>>(ei, eiflag, cnt, E, Nn);
    scan_k<<<1, 1024, 0, stream>>>(cnt, rowp, Nn);
    (void)hipMemsetAsync(scsr, 0, (size_t)Ecap * 4, stream);          // dummy src = 0
    (void)hipMemsetAsync(wbuf, 0, (size_t)6 * Ecap * 4, stream);      // dummy w = 0
    fill_csr_k<<<(E2 + 255) / 256, 256, 0, stream>>>(ei, eiflag, rowp, cnt, scsr, E, Nn);
    // cnt now holds real degrees

    // ---- layer 1: 50 -> 4x256 concat ----
    gemm256_bt2<<<dim3(8, Mpad / 256), 512, 0, stream>>>(xp, WTcat1, XL, SK, Mpad, 64);
    alpha_k<<<(Nn * 4 * 64) / 256, 256, 0, stream>>>(XL, 2, as1, ad1, asrcb, adstb, Nn, 4, 256);
    attn_k<<<(Nn + 3) / 4, 256, 0, stream>>>(rowp, cnt, scsr, asrcb, adstb, wbuf, Nn, 4, Ecap);
    agg_skip8<<<dim3((Nn + 3) / 4, 8), 256, 0, stream>>>(XL, wbuf, rowp, scsr, b1, sb1, SK, Nn, Ecap);
    ln_elu_k<<<Mpad, 256, 0, stream>>>(SK, g1, be1, H1, Nn);

    // ---- layer 2: 1024 -> 4x256 concat ----
    gemm256_bt2<<<dim3(8, Mpad / 256), 512, 0, stream>>>(H1, WTcat2, XL, SK, Mpad, 1024);
    alpha_k<<<(Nn * 4 * 64) / 256, 256, 0, stream>>>(XL, 2, as2, ad2, asrcb, adstb, Nn, 4, 256);
    attn_k<<<(Nn + 3) / 4, 256, 0, stream>>>(rowp, cnt, scsr, asrcb, adstb, wbuf, Nn, 4, Ecap);
    agg_skip8<<<dim3((Nn + 3) / 4, 8), 256, 0, stream>>>(XL, wbuf, rowp, scsr, b2, sb2, SK, Nn, Ecap);
    ln_elu_k<<<Mpad, 256, 0, stream>>>(SK, g2, be2, H1, Nn);  // H1 := h2

    // ---- layer 3: 1024 -> 6x(121 pad 128), mean over heads ----
    gemm256_bt<<<dim3(3, Mpad / 256), 512, 0, stream>>>(H1, W3pT, XL, Mpad, 768, 1024);
    alpha_k<<<(Nn * 6 * 64) / 256, 256, 0, stream>>>(XL, 1, as3, ad3, asrcb, adstb, Nn, 6, 121);
    attn_k<<<(Nn + 3) / 4, 256, 0, stream>>>(rowp, cnt, scsr, asrcb, adstb, wbuf, Nn, 6, Ecap);
    agg_mean8<<<dim3((Nn + 3) / 4, 6), 256, 0, stream>>>(XL, wbuf, rowp, scsr, part, Nn, Ecap);
    reduce_mean_k<<<Nn, 128, 0, stream>>>(part, b3, out, Nn);
}